// Round 7
// baseline (1383.228 us; speedup 1.0000x reference)
//
#include <hip/hip_runtime.h>
#include <hip/hip_bf16.h>

// HMM forward on MI355X — A in MX-fp4 (per-32-block e8m0 scales, 2x MFMA rate),
// v in fp8 (x256), register-resident A, 1-step register prefetch of E/G rows,
// reduction off the recurrence.
// Per step: acc = A v via 128 x mfma_scale_f32_16x16x128_f8f6f4 (A fmt=fp4 cbsz=4,
// B fmt=fp8 blgp=0, B scales unit); S~ = G[x_t]·v overlapped with MFMA issue;
// w = E ⊙ acc; v' = w/S~ (fp8 x256 LDS double-buffer); L += log S~. S~ error
// cancels exactly; final step does one exact reduction: out = L + log(Σw) − Tb·ln256.
// The x256 on A is folded into the e8m0 block scales -> accounting identical to r6.

typedef unsigned long long u64;
typedef unsigned int u32;
typedef unsigned short u16;
using f32x4 = __attribute__((ext_vector_type(4))) float;
using i32x8 = __attribute__((ext_vector_type(8))) int;

#define N_ST 512
#define VOCAB 10000
#define BATCH 64
#define T_MAX 1024

// ---------------- workspace layout (bytes) ----------------
#define WS_EB       0          // E bf16: 10000*512*2 = 10,240,000
#define WS_GB       10240000   // G bf16: 10,240,000
#define WS_A4       20480000   // 128 frags * 64 lanes * 16 B = 131,072 (fp4 nibbles)
#define WS_ASC      20611072   // per-lane scale bytes: 8w*4ks*64l*4B = 32,768
#define WS_ROWLSE   20643840   // 512 f32
#define WS_COLLSE   20645888   // 512 f32
#define WS_PINORM   20647936   // 512 f32
// total 20,649,984 bytes (< r6's 20,748,288 proven footprint)

// ---- bf16 helpers ----
static __device__ __forceinline__ float bf16f(u16 h) {
    return __uint_as_float((u32)h << 16);
}
static __device__ __forceinline__ u16 bf16enc(float f) {
    u32 u = __float_as_uint(f);
    return (u16)((u + 0x7fffu + ((u >> 16) & 1u)) >> 16);
}

// ---- positive OCP e4m3fn decode ----
static __device__ __forceinline__ float dec8(u32 b) {
    float nrm = __uint_as_float((b << 20) + 0x3C000000u);
    float dnm = (float)b * 0x1p-9f;
    return b >= 8u ? nrm : dnm;
}

// ---- software e4m3fn encoder (fallback only) ----
static __device__ __forceinline__ u32 enc_e4m3(float f) {
    if (!(f > 0.f)) return 0u;
    unsigned u = __float_as_uint(f);
    int e = (int)((u >> 23) & 0xff) - 127;
    unsigned m = u & 0x7fffffu;
    if (e > 8 || (e == 8 && m >= 0x700000u)) return 0x7eu;
    if (e >= -6) {
        unsigned mant = m >> 20;
        unsigned rest = m & 0xfffffu;
        if (rest > 0x80000u || (rest == 0x80000u && (mant & 1u))) mant++;
        unsigned r = ((unsigned)(e + 7) << 3) + mant;
        return r > 0x7eu ? 0x7eu : r;
    }
    if (e < -10) return 0u;
    unsigned full = 0x800000u | m;
    int shift = 23 - (e + 9);
    unsigned r = full >> shift;
    unsigned rem = full & ((1u << shift) - 1u);
    unsigned half = 1u << (shift - 1);
    if (rem > half || (rem == half && (r & 1u))) r++;
    return r;
}

template <bool HI>
static __device__ __forceinline__ u32 cvtpk2(float a, float b, u32 old) {
#if __has_builtin(__builtin_amdgcn_cvt_pk_fp8_f32)
    return (u32)__builtin_amdgcn_cvt_pk_fp8_f32(a, b, (int)old, HI);
#else
    unsigned v = enc_e4m3(a) | (enc_e4m3(b) << 8);
    return HI ? ((old & 0x0000ffffu) | (v << 16)) : ((old & 0xffff0000u) | v);
#endif
}

// ---- rowLSE[n] = logsumexp_m emit[n, m] ----
__global__ __launch_bounds__(256) void k_row_lse(const float* __restrict__ emit,
                                                 float* __restrict__ rowLSE) {
    const int n = blockIdx.x;
    const float* row = emit + (size_t)n * VOCAB;
    __shared__ float redm[4], reds[4];
    const int tid = threadIdx.x, lane = tid & 63, wid = tid >> 6;

    float m = -INFINITY;
    for (int i = tid; i < VOCAB; i += 256) m = fmaxf(m, row[i]);
    #pragma unroll
    for (int o = 32; o; o >>= 1) m = fmaxf(m, __shfl_down(m, o));
    if (lane == 0) redm[wid] = m;
    __syncthreads();
    if (tid == 0) redm[0] = fmaxf(fmaxf(redm[0], redm[1]), fmaxf(redm[2], redm[3]));
    __syncthreads();
    m = redm[0];

    float s = 0.f;
    for (int i = tid; i < VOCAB; i += 256) s += __expf(row[i] - m);
    #pragma unroll
    for (int o = 32; o; o >>= 1) s += __shfl_down(s, o);
    if (lane == 0) reds[wid] = s;
    __syncthreads();
    if (tid == 0) rowLSE[n] = m + __logf(reds[0] + reds[1] + reds[2] + reds[3]);
}

// ---- Eb[m*512+n] = bf16( exp(emit[n,m] - rowLSE[n]) ) ----
__global__ __launch_bounds__(256) void k_expEmitT(const float* __restrict__ emit,
                                                  const float* __restrict__ rowLSE,
                                                  u16* __restrict__ Eb) {
    const size_t gid = (size_t)blockIdx.x * 256 + threadIdx.x;
    const int m = (int)(gid >> 9);
    const int n = (int)(gid & 511);
    Eb[gid] = bf16enc(__expf(emit[(size_t)n * VOCAB + m] - rowLSE[n]));
}

// ---- colLSE[k] = logsumexp_j trans[j, k] ----
__global__ __launch_bounds__(256) void k_col_lse(const float* __restrict__ trans,
                                                 float* __restrict__ colLSE) {
    const int k = blockIdx.x;
    const int tid = threadIdx.x, lane = tid & 63, wid = tid >> 6;
    __shared__ float redm[4], reds[4];

    float a = trans[(size_t)tid * N_ST + k];
    float b = trans[(size_t)(tid + 256) * N_ST + k];
    float m = fmaxf(a, b);
    #pragma unroll
    for (int o = 32; o; o >>= 1) m = fmaxf(m, __shfl_down(m, o));
    if (lane == 0) redm[wid] = m;
    __syncthreads();
    if (tid == 0) redm[0] = fmaxf(fmaxf(redm[0], redm[1]), fmaxf(redm[2], redm[3]));
    __syncthreads();
    m = redm[0];

    float s = __expf(a - m) + __expf(b - m);
    #pragma unroll
    for (int o = 32; o; o >>= 1) s += __shfl_down(s, o);
    if (lane == 0) reds[wid] = s;
    __syncthreads();
    if (tid == 0) colLSE[k] = m + __logf(reds[0] + reds[1] + reds[2] + reds[3]);
}

// ---- pack A (column-softmax of trans, x256 folded into scales) into fp4 frags ----
// frag f = w*16 + ks*4 + jt; lane l: j = w*64 + jt*16 + (l&15),
// k-block = ks*128 + (l>>4)*32 + [0,32). Nibble i of dword d = k-offset d*8+i.
// Scale byte for frag f stored at ASC dword (w*4+ks)*64 + l, byte position jt.
__global__ __launch_bounds__(64) void k_packA_fp4(const float* __restrict__ trans,
                                                  const float* __restrict__ colLSE,
                                                  u32* __restrict__ A4,
                                                  unsigned char* __restrict__ ASC) {
    const int f = blockIdx.x;        // 0..127
    const int l = threadIdx.x;       // 0..63
    const int w = f >> 4, ks = (f >> 2) & 3, jt = f & 3;
    const int j = w * 64 + jt * 16 + (l & 15);
    const int k0 = ks * 128 + (l >> 4) * 32;

    float e[32];
    float m = 0.f;
    #pragma unroll
    for (int k = 0; k < 32; ++k) {
        e[k] = 256.0f * __expf(trans[(size_t)j * N_ST + k0 + k] - colLSE[k0 + k]);
        m = fmaxf(m, e[k]);
    }
    const int eexp = (int)ceilf(log2f(m * (1.0f / 6.0f)));   // m/2^eexp in (3,6]
    const float inv = exp2f((float)(-eexp));

    u32 dw[4] = {0u, 0u, 0u, 0u};
    #pragma unroll
    for (int k = 0; k < 32; ++k) {
        const float xv = e[k] * inv;   // (0, 6]
        u32 q = xv < 0.25f ? 0u : xv < 0.75f ? 1u : xv < 1.25f ? 2u :
                xv < 1.75f ? 3u : xv < 2.5f  ? 4u : xv < 3.5f  ? 5u :
                xv < 5.0f  ? 6u : 7u;     // e2m1: {0,.5,1,1.5,2,3,4,6}
        dw[k >> 3] |= q << (4 * (k & 7));
    }
    u32* dst = A4 + (size_t)f * 256 + l * 4;
    *(uint4*)dst = make_uint4(dw[0], dw[1], dw[2], dw[3]);
    ASC[(size_t)(((w * 4 + ks) * 64 + l) * 4) + jt] = (unsigned char)(127 + eexp);
}

// ---- pinorm[j] = softmax(priors)[j] ----
__global__ __launch_bounds__(512) void k_pinorm(const float* __restrict__ priors,
                                                float* __restrict__ pinorm) {
    const int j = threadIdx.x, lane = j & 63, wid = j >> 6;
    __shared__ float redm[8], reds[8];
    float v = priors[j];

    float m = v;
    #pragma unroll
    for (int o = 32; o; o >>= 1) m = fmaxf(m, __shfl_down(m, o));
    if (lane == 0) redm[wid] = m;
    __syncthreads();
    if (j == 0) {
        float r = redm[0];
        for (int i = 1; i < 8; ++i) r = fmaxf(r, redm[i]);
        redm[0] = r;
    }
    __syncthreads();
    m = redm[0];

    float s = __expf(v - m);
    #pragma unroll
    for (int o = 32; o; o >>= 1) s += __shfl_down(s, o);
    if (lane == 0) reds[wid] = s;
    __syncthreads();
    if (j == 0) {
        float r = 0.f;
        for (int i = 0; i < 8; ++i) r += reds[i];
        reds[0] = r;
    }
    __syncthreads();
    pinorm[j] = __expf(v - m) / reds[0];
}

// ---- G[m][k] = sum_j E[m][j] * A[j][k]  (true A; S~ cancellation is exact) ----
__global__ __launch_bounds__(256) void k_G(const u16* __restrict__ Eb,
                                           const float* __restrict__ trans,
                                           const float* __restrict__ colLSE,
                                           u16* __restrict__ Gb) {
    __shared__ float Es[16][512];
    const int m0 = blockIdx.x * 16;
    const int tid = threadIdx.x;
    for (int idx = tid; idx < 16 * 512; idx += 256)
        Es[idx >> 9][idx & 511] = bf16f(Eb[(size_t)(m0 + (idx >> 9)) * 512 + (idx & 511)]);
    __syncthreads();

    const int k0 = tid, k1 = tid + 256;
    const float c0 = colLSE[k0], c1 = colLSE[k1];
    float acc0[16], acc1[16];
    #pragma unroll
    for (int mi = 0; mi < 16; ++mi) { acc0[mi] = 0.f; acc1[mi] = 0.f; }

    for (int j = 0; j < 512; ++j) {
        float a0 = __expf(trans[(size_t)j * N_ST + k0] - c0);
        float a1 = __expf(trans[(size_t)j * N_ST + k1] - c1);
        #pragma unroll
        for (int mi = 0; mi < 16; ++mi) {
            float e = Es[mi][j];
            acc0[mi] = fmaf(e, a0, acc0[mi]);
            acc1[mi] = fmaf(e, a1, acc1[mi]);
        }
    }
    #pragma unroll
    for (int mi = 0; mi < 16; ++mi) {
        Gb[(size_t)(m0 + mi) * N_ST + k0] = bf16enc(acc0[mi]);
        Gb[(size_t)(m0 + mi) * N_ST + k1] = bf16enc(acc1[mi]);
    }
}

#define UNIT_SCALES 0x7f7f7f7f   // 4x e8m0 "1.0" (B operand)
#define AFRAG(i) (i32x8{(int)af[i].x, (int)af[i].y, (int)af[i].z, (int)af[i].w, 0, 0, 0, 0})

// one HMM step; EU/GU = current-step E/G regs, EP/GP = prefetch targets
#define STEP_BODY(EU, GU, EP, GP)                                               \
  {                                                                             \
    const int xpre = xnext;                                                     \
    GP = *(const uint4*)((const char*)Gb + ((size_t)xpre << 10) + (l << 4));    \
    _Pragma("unroll")                                                           \
    for (int jt = 0; jt < 4; ++jt)                                              \
      EP[jt] = *(const u64*)(Eb + (size_t)xpre * N_ST + wbase + jt * 16 + rbase); \
    xnext = xb[(t + 2 <= Tf) ? (t + 2) : Tf];                                   \
    const u64 vown = vq[p][l];                                                  \
    const u32* vbase = (const u32*)&vq[p][0];                                   \
    f32x4 ac0={0,0,0,0}, ac1={0,0,0,0}, ac2={0,0,0,0}, ac3={0,0,0,0};           \
    _Pragma("unroll")                                                           \
    for (int ks = 0; ks < 4; ++ks) {                                            \
      const uint4 b0 = *(const uint4*)(vbase + ks * 32 + grp * 8);              \
      const uint4 b1 = *(const uint4*)(vbase + ks * 32 + grp * 8 + 4);          \
      const i32x8 bq = {(int)b0.x, (int)b0.y, (int)b0.z, (int)b0.w,             \
                        (int)b1.x, (int)b1.y, (int)b1.z, (int)b1.w};            \
      ac0 = __builtin_amdgcn_mfma_scale_f32_16x16x128_f8f6f4(                   \
                AFRAG(ks * 4 + 0), bq, ac0, 4, 0, 0, (int)asc[ks], 0, UNIT_SCALES); \
      ac1 = __builtin_amdgcn_mfma_scale_f32_16x16x128_f8f6f4(                   \
                AFRAG(ks * 4 + 1), bq, ac1, 4, 0, 1, (int)asc[ks], 0, UNIT_SCALES); \
      ac2 = __builtin_amdgcn_mfma_scale_f32_16x16x128_f8f6f4(                   \
                AFRAG(ks * 4 + 2), bq, ac2, 4, 0, 2, (int)asc[ks], 0, UNIT_SCALES); \
      ac3 = __builtin_amdgcn_mfma_scale_f32_16x16x128_f8f6f4(                   \
                AFRAG(ks * 4 + 3), bq, ac3, 4, 0, 3, (int)asc[ks], 0, UNIT_SCALES); \
    }                                                                           \
    float gv = 0.f;                                                             \
    {                                                                           \
      const u32 gw[4] = {GU.x, GU.y, GU.z, GU.w};                               \
      _Pragma("unroll")                                                         \
      for (int i = 0; i < 4; ++i) {                                             \
        float g0 = bf16f((u16)(gw[i] & 0xffffu));                               \
        float g1 = bf16f((u16)(gw[i] >> 16));                                   \
        float v0 = dec8((u32)(vown >> (16 * i)) & 0xffu);                       \
        float v1 = dec8((u32)(vown >> (16 * i + 8)) & 0xffu);                   \
        gv = fmaf(g0, v0, gv);                                                  \
        gv = fmaf(g1, v1, gv);                                                  \
      }                                                                         \
      _Pragma("unroll")                                                         \
      for (int o = 1; o <= 32; o <<= 1) gv += __shfl_xor(gv, o);                \
    }                                                                           \
    float wv2[16];                                                              \
    _Pragma("unroll")                                                           \
    for (int r = 0; r < 4; ++r) {                                               \
      wv2[0 + r]  = bf16f((u16)(EU[0] >> (16 * r))) * ac0[r];                   \
      wv2[4 + r]  = bf16f((u16)(EU[1] >> (16 * r))) * ac1[r];                   \
      wv2[8 + r]  = bf16f((u16)(EU[2] >> (16 * r))) * ac2[r];                   \
      wv2[12 + r] = bf16f((u16)(EU[3] >> (16 * r))) * ac3[r];                   \
    }                                                                           \
    if (t == Tf) {                                                              \
      float s2 = 0.f;                                                           \
      _Pragma("unroll")                                                         \
      for (int i = 0; i < 16; ++i) s2 += wv2[i];                                \
      s2 += __shfl_xor(s2, 16);                                                 \
      s2 += __shfl_xor(s2, 32);                                                 \
      if (l == 0) red[wid] = s2;                                                \
      __syncthreads();                                                          \
      const float Se = red[0] + red[1] + red[2] + red[3] +                      \
                       red[4] + red[5] + red[6] + red[7];                       \
      if (tid == 0) out[b] = L + __logf(Se) - (float)Tb * LN256;                \
    } else {                                                                    \
      L += __logf(gv);                                                          \
      const float sc = 1.0f / gv;                                               \
      if ((l & 15) == 0) {                                                      \
        u32* vw = (u32*)&vq[p ^ 1][0];                                          \
        _Pragma("unroll")                                                       \
        for (int jt = 0; jt < 4; ++jt) {                                        \
          u32 pk = cvtpk2<false>(wv2[jt * 4 + 0] * sc, wv2[jt * 4 + 1] * sc, 0u); \
          pk = cvtpk2<true>(wv2[jt * 4 + 2] * sc, wv2[jt * 4 + 3] * sc, pk);    \
          vw[(wbase >> 2) + jt * 4 + grp] = pk;                                 \
        }                                                                       \
      }                                                                         \
      __syncthreads();                                                          \
      p ^= 1;                                                                   \
    }                                                                           \
  }

// ---- main: one WG per chain; 8 waves x 64 states; A resident (fp4 frags) ----
__global__ __launch_bounds__(512, 2) void hmm_main(const int* __restrict__ x,
                                                   const int* __restrict__ T,
                                                   const u16* __restrict__ Eb,
                                                   const u32* __restrict__ A4,
                                                   const u32* __restrict__ ASC,
                                                   const u16* __restrict__ Gb,
                                                   const float* __restrict__ pinorm,
                                                   float* __restrict__ out) {
    __shared__ u64 vq[2][64];
    __shared__ float red[8];
    const int b = blockIdx.x;
    const int tid = threadIdx.x;
    const int l = tid & 63;
    const int wid = tid >> 6;
    const int grp = l >> 4;
    const int wbase = wid * 64;
    const int rbase = grp * 4;
    const float LN256 = 5.545177444479562f;

    int Tb = T[b];
    Tb = Tb < 1 ? 1 : (Tb > T_MAX ? T_MAX : Tb);
    const int* xb = x + (size_t)b * T_MAX;

    // resident A fragments: 16 x 16 B per lane (64 VGPRs) + 4 scale dwords
    uint4 af[16];
    u32 asc[4];
    {
        const u32* ap = A4 + (size_t)wid * 16 * 256 + l * 4;
        #pragma unroll
        for (int i = 0; i < 16; ++i)
            af[i] = *(const uint4*)(ap + (size_t)i * 256);
        #pragma unroll
        for (int d = 0; d < 4; ++d)
            asc[d] = ASC[(wid * 4 + d) * 64 + l];
    }

    // prefetch E/G for t=1 immediately (x known upfront; harmless if Tb==1)
    const int x0 = xb[0];
    const int x1 = xb[1];
    u64 eA[4], eB[4];
    uint4 gA, gB;
    gA = *(const uint4*)((const char*)Gb + ((size_t)x1 << 10) + (l << 4));
    #pragma unroll
    for (int jt = 0; jt < 4; ++jt)
        eA[jt] = *(const u64*)(Eb + (size_t)x1 * N_ST + wbase + jt * 16 + rbase);

    // ---- t = 0 ----
    float wv[16];
    float s = 0.f;
    #pragma unroll
    for (int jt = 0; jt < 4; ++jt) {
        u64 eraw = *(const u64*)(Eb + (size_t)x0 * N_ST + wbase + jt * 16 + rbase);
        #pragma unroll
        for (int r = 0; r < 4; ++r) {
            const int j = wbase + jt * 16 + rbase + r;
            float e = bf16f((u16)(eraw >> (16 * r)));
            float t0 = e * pinorm[j];
            wv[jt * 4 + r] = t0;
            s += t0;
        }
    }
    s += __shfl_xor(s, 16);
    s += __shfl_xor(s, 32);
    if (l == 0) red[wid] = s;
    __syncthreads();
    float S0 = red[0] + red[1] + red[2] + red[3] + red[4] + red[5] + red[6] + red[7];
    float L = __logf(S0);
    if (Tb == 1) {
        if (tid == 0) out[b] = L;
        return;
    }
    __syncthreads();
    {
        const float sc = 256.0f / S0;
        if ((l & 15) == 0) {
            u32* vw = (u32*)&vq[0][0];
            #pragma unroll
            for (int jt = 0; jt < 4; ++jt) {
                u32 pk = cvtpk2<false>(wv[jt * 4 + 0] * sc, wv[jt * 4 + 1] * sc, 0u);
                pk = cvtpk2<true>(wv[jt * 4 + 2] * sc, wv[jt * 4 + 3] * sc, pk);
                vw[(wbase >> 2) + jt * 4 + grp] = pk;
            }
        }
    }
    __syncthreads();

    // ---- t = 1 .. Tb-1 (unroll-2 with register E/G double-buffer) ----
    const int Tf = Tb - 1;
    int p = 0;
    int xnext = xb[(2 <= Tf) ? 2 : Tf];
    for (int t = 1;;) {
        STEP_BODY(eA, gA, eB, gB)
        if (t == Tf) break;
        ++t;
        STEP_BODY(eB, gB, eA, gA)
        if (t == Tf) break;
        ++t;
    }
}

extern "C" void kernel_launch(void* const* d_in, const int* in_sizes, int n_in,
                              void* d_out, int out_size, void* d_ws, size_t ws_size,
                              hipStream_t stream) {
    const int*   x      = (const int*)d_in[0];     // (64, 1024)
    const int*   T      = (const int*)d_in[1];     // (64,)
    const float* priors = (const float*)d_in[2];   // (512,)
    const float* trans  = (const float*)d_in[3];   // (512, 512)
    const float* emit   = (const float*)d_in[4];   // (512, 10000)
    float* out = (float*)d_out;                    // (64, 1)

    char* ws = (char*)d_ws;
    u16*   Eb     = (u16*)(ws + WS_EB);
    u16*   Gb     = (u16*)(ws + WS_GB);
    u32*   A4     = (u32*)(ws + WS_A4);
    unsigned char* ASCb = (unsigned char*)(ws + WS_ASC);
    float* rowLSE = (float*)(ws + WS_ROWLSE);
    float* colLSE = (float*)(ws + WS_COLLSE);
    float* pinorm = (float*)(ws + WS_PINORM);

    k_row_lse<<<N_ST, 256, 0, stream>>>(emit, rowLSE);
    k_expEmitT<<<(VOCAB * N_ST) / 256, 256, 0, stream>>>(emit, rowLSE, Eb);
    k_col_lse<<<N_ST, 256, 0, stream>>>(trans, colLSE);
    k_packA_fp4<<<128, 64, 0, stream>>>(trans, colLSE, A4, ASCb);
    k_pinorm<<<1, 512, 0, stream>>>(priors, pinorm);
    k_G<<<VOCAB / 16, 256, 0, stream>>>(Eb, trans, colLSE, Gb);

    hmm_main<<<BATCH, 512, 0, stream>>>(x, T, Eb, A4, (const u32*)ASCb, Gb, pinorm, out);
}

// Round 8
// 1293.643 us; speedup vs baseline: 1.0693x; 1.0693x over previous
//
#include <hip/hip_runtime.h>
#include <hip/hip_bf16.h>

// HMM forward on MI355X — K=128 MX-fp8 MFMA (unit scales), register-resident A,
// 1-step register prefetch of E/G rows, reduction off the recurrence,
// RAW s_barrier (lgkmcnt-only drain: vmem prefetch spans the barrier).
// Per step: acc = A v via 16/wave mfma_scale_f32_16x16x128_f8f6f4 (8 chains x depth 2);
// S~ = G[x_t]·v (G = E^T A, bf16) overlapped with MFMA issue; w = E ⊙ acc;
// v' = w/S~ (fp8 x256 LDS double-buffer); L += log S~. S~ error cancels exactly;
// final step does one exact reduction: out = L + log(Σw) − Tb·ln256.

typedef unsigned long long u64;
typedef unsigned int u32;
typedef unsigned short u16;
using f32x4 = __attribute__((ext_vector_type(4))) float;
using i32x8 = __attribute__((ext_vector_type(8))) int;

#define N_ST 512
#define VOCAB 10000
#define BATCH 64
#define T_MAX 1024

// ---------------- workspace layout (bytes) ----------------
#define WS_EB       0          // E bf16: 10000*512*2 = 10,240,000
#define WS_GB       10240000   // G bf16: 10,240,000
#define WS_A8       20480000   // 128 frags * 2048 B = 262,144
#define WS_ROWLSE   20742144   // 512 f32
#define WS_COLLSE   20744192   // 512 f32
#define WS_PINORM   20746240   // 512 f32

// ---- bf16 helpers ----
static __device__ __forceinline__ float bf16f(u16 h) {
    return __uint_as_float((u32)h << 16);
}
static __device__ __forceinline__ u16 bf16enc(float f) {
    u32 u = __float_as_uint(f);
    return (u16)((u + 0x7fffu + ((u >> 16) & 1u)) >> 16);
}

// ---- positive OCP e4m3fn decode ----
static __device__ __forceinline__ float dec8(u32 b) {
    float nrm = __uint_as_float((b << 20) + 0x3C000000u);
    float dnm = (float)b * 0x1p-9f;
    return b >= 8u ? nrm : dnm;
}

// ---- software e4m3fn encoder (fallback only) ----
static __device__ __forceinline__ u32 enc_e4m3(float f) {
    if (!(f > 0.f)) return 0u;
    unsigned u = __float_as_uint(f);
    int e = (int)((u >> 23) & 0xff) - 127;
    unsigned m = u & 0x7fffffu;
    if (e > 8 || (e == 8 && m >= 0x700000u)) return 0x7eu;
    if (e >= -6) {
        unsigned mant = m >> 20;
        unsigned rest = m & 0xfffffu;
        if (rest > 0x80000u || (rest == 0x80000u && (mant & 1u))) mant++;
        unsigned r = ((unsigned)(e + 7) << 3) + mant;
        return r > 0x7eu ? 0x7eu : r;
    }
    if (e < -10) return 0u;
    unsigned full = 0x800000u | m;
    int shift = 23 - (e + 9);
    unsigned r = full >> shift;
    unsigned rem = full & ((1u << shift) - 1u);
    unsigned half = 1u << (shift - 1);
    if (rem > half || (rem == half && (r & 1u))) r++;
    return r;
}

template <bool HI>
static __device__ __forceinline__ u32 cvtpk2(float a, float b, u32 old) {
#if __has_builtin(__builtin_amdgcn_cvt_pk_fp8_f32)
    return (u32)__builtin_amdgcn_cvt_pk_fp8_f32(a, b, (int)old, HI);
#else
    unsigned v = enc_e4m3(a) | (enc_e4m3(b) << 8);
    return HI ? ((old & 0x0000ffffu) | (v << 16)) : ((old & 0xffff0000u) | v);
#endif
}

// ---- rowLSE[n] = logsumexp_m emit[n, m] ----
__global__ __launch_bounds__(256) void k_row_lse(const float* __restrict__ emit,
                                                 float* __restrict__ rowLSE) {
    const int n = blockIdx.x;
    const float* row = emit + (size_t)n * VOCAB;
    __shared__ float redm[4], reds[4];
    const int tid = threadIdx.x, lane = tid & 63, wid = tid >> 6;

    float m = -INFINITY;
    for (int i = tid; i < VOCAB; i += 256) m = fmaxf(m, row[i]);
    #pragma unroll
    for (int o = 32; o; o >>= 1) m = fmaxf(m, __shfl_down(m, o));
    if (lane == 0) redm[wid] = m;
    __syncthreads();
    if (tid == 0) redm[0] = fmaxf(fmaxf(redm[0], redm[1]), fmaxf(redm[2], redm[3]));
    __syncthreads();
    m = redm[0];

    float s = 0.f;
    for (int i = tid; i < VOCAB; i += 256) s += __expf(row[i] - m);
    #pragma unroll
    for (int o = 32; o; o >>= 1) s += __shfl_down(s, o);
    if (lane == 0) reds[wid] = s;
    __syncthreads();
    if (tid == 0) rowLSE[n] = m + __logf(reds[0] + reds[1] + reds[2] + reds[3]);
}

// ---- Eb[m*512+n] = bf16( exp(emit[n,m] - rowLSE[n]) ) ----
__global__ __launch_bounds__(256) void k_expEmitT(const float* __restrict__ emit,
                                                  const float* __restrict__ rowLSE,
                                                  u16* __restrict__ Eb) {
    const size_t gid = (size_t)blockIdx.x * 256 + threadIdx.x;
    const int m = (int)(gid >> 9);
    const int n = (int)(gid & 511);
    Eb[gid] = bf16enc(__expf(emit[(size_t)n * VOCAB + m] - rowLSE[n]));
}

// ---- colLSE[k] = logsumexp_j trans[j, k] ----
__global__ __launch_bounds__(256) void k_col_lse(const float* __restrict__ trans,
                                                 float* __restrict__ colLSE) {
    const int k = blockIdx.x;
    const int tid = threadIdx.x, lane = tid & 63, wid = tid >> 6;
    __shared__ float redm[4], reds[4];

    float a = trans[(size_t)tid * N_ST + k];
    float b = trans[(size_t)(tid + 256) * N_ST + k];
    float m = fmaxf(a, b);
    #pragma unroll
    for (int o = 32; o; o >>= 1) m = fmaxf(m, __shfl_down(m, o));
    if (lane == 0) redm[wid] = m;
    __syncthreads();
    if (tid == 0) redm[0] = fmaxf(fmaxf(redm[0], redm[1]), fmaxf(redm[2], redm[3]));
    __syncthreads();
    m = redm[0];

    float s = __expf(a - m) + __expf(b - m);
    #pragma unroll
    for (int o = 32; o; o >>= 1) s += __shfl_down(s, o);
    if (lane == 0) reds[wid] = s;
    __syncthreads();
    if (tid == 0) colLSE[k] = m + __logf(reds[0] + reds[1] + reds[2] + reds[3]);
}

// ---- pack A (column-softmax of trans, x256) into fp8 K=128 MFMA A-fragments ----
// frag f = w*16 + ks*4 + jt  (w=wave, ks=k-slice of 128, jt=j-tile of 16)
// lane l, byte i (0..31): A[j][k], j = w*64 + jt*16 + (l&15),
//                                  k = ks*128 + (l>>4)*32 + i
__global__ __launch_bounds__(64) void k_packA_fp8(const float* __restrict__ trans,
                                                  const float* __restrict__ colLSE,
                                                  u32* __restrict__ A8) {
    const int f = blockIdx.x;        // 0..127
    const int l = threadIdx.x;       // 0..63
    const int w = f >> 4, ks = (f >> 2) & 3, jt = f & 3;
    const int j = w * 64 + jt * 16 + (l & 15);
    const int k0 = ks * 128 + (l >> 4) * 32;
    u32 dw[8];
    #pragma unroll
    for (int d = 0; d < 8; ++d) {
        float a0 = 256.0f * __expf(trans[(size_t)j * N_ST + k0 + 4 * d + 0] - colLSE[k0 + 4 * d + 0]);
        float a1 = 256.0f * __expf(trans[(size_t)j * N_ST + k0 + 4 * d + 1] - colLSE[k0 + 4 * d + 1]);
        float a2 = 256.0f * __expf(trans[(size_t)j * N_ST + k0 + 4 * d + 2] - colLSE[k0 + 4 * d + 2]);
        float a3 = 256.0f * __expf(trans[(size_t)j * N_ST + k0 + 4 * d + 3] - colLSE[k0 + 4 * d + 3]);
        u32 pk = cvtpk2<false>(a0, a1, 0u);
        dw[d] = cvtpk2<true>(a2, a3, pk);
    }
    u32* dst = A8 + (size_t)f * 512 + l * 8;
    *(uint4*)dst       = make_uint4(dw[0], dw[1], dw[2], dw[3]);
    *(uint4*)(dst + 4) = make_uint4(dw[4], dw[5], dw[6], dw[7]);
}

// ---- pinorm[j] = softmax(priors)[j] ----
__global__ __launch_bounds__(512) void k_pinorm(const float* __restrict__ priors,
                                                float* __restrict__ pinorm) {
    const int j = threadIdx.x, lane = j & 63, wid = j >> 6;
    __shared__ float redm[8], reds[8];
    float v = priors[j];

    float m = v;
    #pragma unroll
    for (int o = 32; o; o >>= 1) m = fmaxf(m, __shfl_down(m, o));
    if (lane == 0) redm[wid] = m;
    __syncthreads();
    if (j == 0) {
        float r = redm[0];
        for (int i = 1; i < 8; ++i) r = fmaxf(r, redm[i]);
        redm[0] = r;
    }
    __syncthreads();
    m = redm[0];

    float s = __expf(v - m);
    #pragma unroll
    for (int o = 32; o; o >>= 1) s += __shfl_down(s, o);
    if (lane == 0) reds[wid] = s;
    __syncthreads();
    if (j == 0) {
        float r = 0.f;
        for (int i = 0; i < 8; ++i) r += reds[i];
        reds[0] = r;
    }
    __syncthreads();
    pinorm[j] = __expf(v - m) / reds[0];
}

// ---- G[m][k] = sum_j E[m][j] * A[j][k] ----
__global__ __launch_bounds__(256) void k_G(const u16* __restrict__ Eb,
                                           const float* __restrict__ trans,
                                           const float* __restrict__ colLSE,
                                           u16* __restrict__ Gb) {
    __shared__ float Es[16][512];
    const int m0 = blockIdx.x * 16;
    const int tid = threadIdx.x;
    for (int idx = tid; idx < 16 * 512; idx += 256)
        Es[idx >> 9][idx & 511] = bf16f(Eb[(size_t)(m0 + (idx >> 9)) * 512 + (idx & 511)]);
    __syncthreads();

    const int k0 = tid, k1 = tid + 256;
    const float c0 = colLSE[k0], c1 = colLSE[k1];
    float acc0[16], acc1[16];
    #pragma unroll
    for (int mi = 0; mi < 16; ++mi) { acc0[mi] = 0.f; acc1[mi] = 0.f; }

    for (int j = 0; j < 512; ++j) {
        float a0 = __expf(trans[(size_t)j * N_ST + k0] - c0);
        float a1 = __expf(trans[(size_t)j * N_ST + k1] - c1);
        #pragma unroll
        for (int mi = 0; mi < 16; ++mi) {
            float e = Es[mi][j];
            acc0[mi] = fmaf(e, a0, acc0[mi]);
            acc1[mi] = fmaf(e, a1, acc1[mi]);
        }
    }
    #pragma unroll
    for (int mi = 0; mi < 16; ++mi) {
        Gb[(size_t)(m0 + mi) * N_ST + k0] = bf16enc(acc0[mi]);
        Gb[(size_t)(m0 + mi) * N_ST + k1] = bf16enc(acc1[mi]);
    }
}

#define UNIT_SCALES 0x7f7f7f7f   // 4x e8m0 "1.0"

// raw workgroup barrier: drain LDS only (vmem prefetch stays in flight)
#define WG_BARRIER()                                        \
  {                                                         \
    asm volatile("s_waitcnt lgkmcnt(0)" ::: "memory");      \
    __builtin_amdgcn_s_barrier();                           \
    asm volatile("" ::: "memory");                          \
  }

// one HMM step; EU/GU = current-step E/G regs, EP/GP = prefetch targets
#define STEP_BODY(EU, GU, EP, GP)                                               \
  {                                                                             \
    const int xpre = xnext;                                                     \
    GP = *(const uint4*)((const char*)Gb + ((size_t)xpre << 10) + (l << 4));    \
    _Pragma("unroll")                                                           \
    for (int jt = 0; jt < 4; ++jt)                                              \
      EP[jt] = *(const u64*)(Eb + (size_t)xpre * N_ST + wbase + jt * 16 + rbase); \
    xnext = xb[(t + 2 <= Tf) ? (t + 2) : Tf];                                   \
    const u64 vown = vq[p][l];                                                  \
    const u32* vbase = (const u32*)&vq[p][0];                                   \
    /* hoist all B-operand LDS reads */                                         \
    i32x8 bq[4];                                                                \
    _Pragma("unroll")                                                           \
    for (int ks = 0; ks < 4; ++ks) {                                            \
      const uint4 b0 = *(const uint4*)(vbase + ks * 32 + grp * 8);              \
      const uint4 b1 = *(const uint4*)(vbase + ks * 32 + grp * 8 + 4);          \
      bq[ks] = i32x8{(int)b0.x, (int)b0.y, (int)b0.z, (int)b0.w,                \
                     (int)b1.x, (int)b1.y, (int)b1.z, (int)b1.w};               \
    }                                                                           \
    /* 16 MFMAs as 8 independent chains of depth 2 */                           \
    f32x4 aA0={0,0,0,0}, aA1={0,0,0,0}, aA2={0,0,0,0}, aA3={0,0,0,0};           \
    f32x4 aB0={0,0,0,0}, aB1={0,0,0,0}, aB2={0,0,0,0}, aB3={0,0,0,0};           \
    _Pragma("unroll")                                                           \
    for (int kk = 0; kk < 2; ++kk) {                                            \
      const int ksA = kk * 2, ksB = kk * 2 + 1;                                 \
      aA0 = __builtin_amdgcn_mfma_scale_f32_16x16x128_f8f6f4(                   \
                af[ksA * 4 + 0], bq[ksA], aA0, 0, 0, 0, UNIT_SCALES, 0, UNIT_SCALES); \
      aB0 = __builtin_amdgcn_mfma_scale_f32_16x16x128_f8f6f4(                   \
                af[ksB * 4 + 0], bq[ksB], aB0, 0, 0, 0, UNIT_SCALES, 0, UNIT_SCALES); \
      aA1 = __builtin_amdgcn_mfma_scale_f32_16x16x128_f8f6f4(                   \
                af[ksA * 4 + 1], bq[ksA], aA1, 0, 0, 0, UNIT_SCALES, 0, UNIT_SCALES); \
      aB1 = __builtin_amdgcn_mfma_scale_f32_16x16x128_f8f6f4(                   \
                af[ksB * 4 + 1], bq[ksB], aB1, 0, 0, 0, UNIT_SCALES, 0, UNIT_SCALES); \
      aA2 = __builtin_amdgcn_mfma_scale_f32_16x16x128_f8f6f4(                   \
                af[ksA * 4 + 2], bq[ksA], aA2, 0, 0, 0, UNIT_SCALES, 0, UNIT_SCALES); \
      aB2 = __builtin_amdgcn_mfma_scale_f32_16x16x128_f8f6f4(                   \
                af[ksB * 4 + 2], bq[ksB], aB2, 0, 0, 0, UNIT_SCALES, 0, UNIT_SCALES); \
      aA3 = __builtin_amdgcn_mfma_scale_f32_16x16x128_f8f6f4(                   \
                af[ksA * 4 + 3], bq[ksA], aA3, 0, 0, 0, UNIT_SCALES, 0, UNIT_SCALES); \
      aB3 = __builtin_amdgcn_mfma_scale_f32_16x16x128_f8f6f4(                   \
                af[ksB * 4 + 3], bq[ksB], aB3, 0, 0, 0, UNIT_SCALES, 0, UNIT_SCALES); \
    }                                                                           \
    float gv = 0.f;                                                             \
    {                                                                           \
      const u32 gw[4] = {GU.x, GU.y, GU.z, GU.w};                               \
      _Pragma("unroll")                                                         \
      for (int i = 0; i < 4; ++i) {                                             \
        float g0 = bf16f((u16)(gw[i] & 0xffffu));                               \
        float g1 = bf16f((u16)(gw[i] >> 16));                                   \
        float v0 = dec8((u32)(vown >> (16 * i)) & 0xffu);                       \
        float v1 = dec8((u32)(vown >> (16 * i + 8)) & 0xffu);                   \
        gv = fmaf(g0, v0, gv);                                                  \
        gv = fmaf(g1, v1, gv);                                                  \
      }                                                                         \
      _Pragma("unroll")                                                         \
      for (int o = 1; o <= 32; o <<= 1) gv += __shfl_xor(gv, o);                \
    }                                                                           \
    float wv2[16];                                                              \
    _Pragma("unroll")                                                           \
    for (int r = 0; r < 4; ++r) {                                               \
      wv2[0 + r]  = bf16f((u16)(EU[0] >> (16 * r))) * (aA0[r] + aB0[r]);        \
      wv2[4 + r]  = bf16f((u16)(EU[1] >> (16 * r))) * (aA1[r] + aB1[r]);        \
      wv2[8 + r]  = bf16f((u16)(EU[2] >> (16 * r))) * (aA2[r] + aB2[r]);        \
      wv2[12 + r] = bf16f((u16)(EU[3] >> (16 * r))) * (aA3[r] + aB3[r]);        \
    }                                                                           \
    if (t == Tf) {                                                              \
      float s2 = 0.f;                                                           \
      _Pragma("unroll")                                                         \
      for (int i = 0; i < 16; ++i) s2 += wv2[i];                                \
      s2 += __shfl_xor(s2, 16);                                                 \
      s2 += __shfl_xor(s2, 32);                                                 \
      if (l == 0) red[wid] = s2;                                                \
      __syncthreads();                                                          \
      const float Se = red[0] + red[1] + red[2] + red[3] +                      \
                       red[4] + red[5] + red[6] + red[7];                       \
      if (tid == 0) out[b] = L + __logf(Se) - (float)Tb * LN256;                \
    } else {                                                                    \
      L += __logf(gv);                                                          \
      const float sc = 1.0f / gv;                                               \
      if ((l & 15) == 0) {                                                      \
        u32* vw = (u32*)&vq[p ^ 1][0];                                          \
        _Pragma("unroll")                                                       \
        for (int jt = 0; jt < 4; ++jt) {                                        \
          u32 pk = cvtpk2<false>(wv2[jt * 4 + 0] * sc, wv2[jt * 4 + 1] * sc, 0u); \
          pk = cvtpk2<true>(wv2[jt * 4 + 2] * sc, wv2[jt * 4 + 3] * sc, pk);    \
          vw[(wbase >> 2) + jt * 4 + grp] = pk;                                 \
        }                                                                       \
      }                                                                         \
      WG_BARRIER();                                                             \
      p ^= 1;                                                                   \
    }                                                                           \
  }

// ---- main: one WG per chain; 8 waves x 64 states; A resident (K=128 frags) ----
__global__ __launch_bounds__(512, 2) void hmm_main(const int* __restrict__ x,
                                                   const int* __restrict__ T,
                                                   const u16* __restrict__ Eb,
                                                   const u32* __restrict__ A8,
                                                   const u16* __restrict__ Gb,
                                                   const float* __restrict__ pinorm,
                                                   float* __restrict__ out) {
    __shared__ u64 vq[2][64];
    __shared__ float red[8];
    const int b = blockIdx.x;
    const int tid = threadIdx.x;
    const int l = tid & 63;
    const int wid = tid >> 6;
    const int grp = l >> 4;
    const int wbase = wid * 64;
    const int rbase = grp * 4;
    const float LN256 = 5.545177444479562f;

    int Tb = T[b];
    Tb = Tb < 1 ? 1 : (Tb > T_MAX ? T_MAX : Tb);
    const int* xb = x + (size_t)b * T_MAX;

    // resident A fragments: 16 x 32 B per lane (128 VGPRs)
    i32x8 af[16];
    {
        const u32* ap = A8 + (size_t)wid * 16 * 512 + l * 8;
        #pragma unroll
        for (int i = 0; i < 16; ++i) {
            uint4 lo = *(const uint4*)(ap + (size_t)i * 512);
            uint4 hi = *(const uint4*)(ap + (size_t)i * 512 + 4);
            af[i] = i32x8{(int)lo.x, (int)lo.y, (int)lo.z, (int)lo.w,
                          (int)hi.x, (int)hi.y, (int)hi.z, (int)hi.w};
        }
    }

    // prefetch E/G for t=1 immediately (x known upfront; harmless if Tb==1)
    const int x0 = xb[0];
    const int x1 = xb[1];
    u64 eA[4], eB[4];
    uint4 gA, gB;
    gA = *(const uint4*)((const char*)Gb + ((size_t)x1 << 10) + (l << 4));
    #pragma unroll
    for (int jt = 0; jt < 4; ++jt)
        eA[jt] = *(const u64*)(Eb + (size_t)x1 * N_ST + wbase + jt * 16 + rbase);

    // ---- t = 0 ----
    float wv[16];
    float s = 0.f;
    #pragma unroll
    for (int jt = 0; jt < 4; ++jt) {
        u64 eraw = *(const u64*)(Eb + (size_t)x0 * N_ST + wbase + jt * 16 + rbase);
        #pragma unroll
        for (int r = 0; r < 4; ++r) {
            const int j = wbase + jt * 16 + rbase + r;
            float e = bf16f((u16)(eraw >> (16 * r)));
            float t0 = e * pinorm[j];
            wv[jt * 4 + r] = t0;
            s += t0;
        }
    }
    s += __shfl_xor(s, 16);
    s += __shfl_xor(s, 32);
    if (l == 0) red[wid] = s;
    __syncthreads();
    float S0 = red[0] + red[1] + red[2] + red[3] + red[4] + red[5] + red[6] + red[7];
    float L = __logf(S0);
    if (Tb == 1) {
        if (tid == 0) out[b] = L;
        return;
    }
    __syncthreads();
    {
        const float sc = 256.0f / S0;
        if ((l & 15) == 0) {
            u32* vw = (u32*)&vq[0][0];
            #pragma unroll
            for (int jt = 0; jt < 4; ++jt) {
                u32 pk = cvtpk2<false>(wv[jt * 4 + 0] * sc, wv[jt * 4 + 1] * sc, 0u);
                pk = cvtpk2<true>(wv[jt * 4 + 2] * sc, wv[jt * 4 + 3] * sc, pk);
                vw[(wbase >> 2) + jt * 4 + grp] = pk;
            }
        }
    }
    __syncthreads();

    // ---- t = 1 .. Tb-1 (unroll-2 with register E/G double-buffer) ----
    const int Tf = Tb - 1;
    int p = 0;
    int xnext = xb[(2 <= Tf) ? 2 : Tf];
    for (int t = 1;;) {
        STEP_BODY(eA, gA, eB, gB)
        if (t == Tf) break;
        ++t;
        STEP_BODY(eB, gB, eA, gA)
        if (t == Tf) break;
        ++t;
    }
}

extern "C" void kernel_launch(void* const* d_in, const int* in_sizes, int n_in,
                              void* d_out, int out_size, void* d_ws, size_t ws_size,
                              hipStream_t stream) {
    const int*   x      = (const int*)d_in[0];     // (64, 1024)
    const int*   T      = (const int*)d_in[1];     // (64,)
    const float* priors = (const float*)d_in[2];   // (512,)
    const float* trans  = (const float*)d_in[3];   // (512, 512)
    const float* emit   = (const float*)d_in[4];   // (512, 10000)
    float* out = (float*)d_out;                    // (64, 1)

    char* ws = (char*)d_ws;
    u16*   Eb     = (u16*)(ws + WS_EB);
    u16*   Gb     = (u16*)(ws + WS_GB);
    u32*   A8     = (u32*)(ws + WS_A8);
    float* rowLSE = (float*)(ws + WS_ROWLSE);
    float* colLSE = (float*)(ws + WS_COLLSE);
    float* pinorm = (float*)(ws + WS_PINORM);

    k_row_lse<<<N_ST, 256, 0, stream>>>(emit, rowLSE);
    k_expEmitT<<<(VOCAB * N_ST) / 256, 256, 0, stream>>>(emit, rowLSE, Eb);
    k_col_lse<<<N_ST, 256, 0, stream>>>(trans, colLSE);
    k_packA_fp8<<<128, 64, 0, stream>>>(trans, colLSE, A8);
    k_pinorm<<<1, 512, 0, stream>>>(priors, pinorm);
    k_G<<<VOCAB / 16, 256, 0, stream>>>(Eb, trans, colLSE, Gb);

    hmm_main<<<BATCH, 512, 0, stream>>>(x, T, Eb, A8, Gb, pinorm, out);
}